// Round 3
// baseline (83.843 us; speedup 1.0000x reference)
//
#include <hip/hip_runtime.h>
#include <hip/hip_bf16.h>

typedef __attribute__((ext_vector_type(8))) short short8;
typedef __attribute__((ext_vector_type(16))) float floatx16;

#define B_ROWS 8192
#define DIM    128
#define NSPLIT 16
#define JSPAN  (B_ROWS / NSPLIT)        // 512 cols per split
#define NTILE  (JSPAN / 32)             // 16 j-tiles of 32 cols
#define WAVES  4
#define ROWS_PER_WAVE 32
#define BM     (WAVES * ROWS_PER_WAVE)  // 128 rows per block
#define NRB    (B_ROWS / BM)            // 64 row-blocks
#define BIAS   4096.0f

// ws layout
#define OFF_SQ   (2u << 20)
#define OFF_D2P  (OFF_SQ + (64u << 10))
#define OFF_D2N  (OFF_D2P + (512u << 10))
#define OFF_ACC  (OFF_D2N + (512u << 10))   // float sum, int done

// ---------------- prep: f32 -> bf16 + squared norms + init accumulators ----------------
__global__ __launch_bounds__(256) void prep_kernel(const float* __restrict__ x,
                                                   __hip_bfloat16* __restrict__ xb,
                                                   float* __restrict__ sq,
                                                   float* __restrict__ acc_sum,
                                                   int* __restrict__ done) {
    if (blockIdx.x == 0 && threadIdx.x == 0) { acc_sum[0] = 0.f; done[0] = 0; }
    const int row  = blockIdx.x * 4 + (threadIdx.x >> 6);
    const int lane = threadIdx.x & 63;
    const float2 v = *reinterpret_cast<const float2*>(x + row * DIM + lane * 2);
    __hip_bfloat162 b2;
    b2.x = __float2bfloat16(v.x);
    b2.y = __float2bfloat16(v.y);
    *reinterpret_cast<__hip_bfloat162*>(xb + row * DIM + lane * 2) = b2;
    float s = v.x * v.x + v.y * v.y;
    #pragma unroll
    for (int m = 1; m < 64; m <<= 1) s += __shfl_xor(s, m, 64);
    if (lane == 0) sq[row] = s;
}

// ---------------- main: barrier-free Gram + biased hardest pos/neg ----------------
// grid = (NRB, NSPLIT), block = 256 (4 independent waves), 4 blocks/CU.
// Wave owns 32 rows; streams the split's 512 cols in 32-col MFMA tiles.
// t = sq_j - 2*dot + BIAS*same.  max over all t -> hardest_pos + BIAS;
// min over all t -> hardest_neg (same-pairs incl. diagonal lifted out of min).
__global__ __launch_bounds__(256, 4) void main_kernel(
    const __hip_bfloat16* __restrict__ xb,
    const float* __restrict__ sq,
    const int*  __restrict__ lab,
    float* __restrict__ d2p,   // [NSPLIT][B_ROWS]
    float* __restrict__ d2n) { // [NSPLIT][B_ROWS]
    const int tid  = threadIdx.x;
    const int lane = tid & 63;
    const int wave = tid >> 6;
    const int l31  = lane & 31;
    const int hi   = lane >> 5;
    const int rowbase = blockIdx.x * BM + wave * ROWS_PER_WAVE;
    const int split   = blockIdx.y;
    const int jstart  = split * JSPAN;

    // A fragments: 32 rows x 128 k.  mfma_f32_32x32x16_bf16 A layout:
    // row = lane&31, k = (lane>>5)*8 + e, advancing 16 per slice.
    short8 a[8];
    {
        const __hip_bfloat16* ap = xb + (size_t)(rowbase + l31) * DIM + hi * 8;
        #pragma unroll
        for (int ks = 0; ks < 8; ++ks)
            a[ks] = *reinterpret_cast<const short8*>(ap + ks * 16);
    }
    // Labels of owned rows per C/D reg (row = (r&3) + 8*(r>>2) + 4*hi)
    int labi[16];
    #pragma unroll
    for (int r = 0; r < 16; ++r)
        labi[r] = lab[rowbase + (r & 3) + 8 * (r >> 2) + 4 * hi];

    float mx[16], mn[16];
    #pragma unroll
    for (int r = 0; r < 16; ++r) { mx[r] = -INFINITY; mn[r] = INFINITY; }

    const __hip_bfloat16* bcol = xb + (size_t)(jstart + l31) * DIM + hi * 8;

    for (int jt = 0; jt < NTILE; ++jt) {
        const int jbase = jstart + jt * 32;
        const float sqj  = sq[jbase + l31];
        const float sqjb = sqj + BIAS;
        const int   labj = lab[jbase + l31];
        const __hip_bfloat16* bp = bcol + (size_t)jt * 32 * DIM;
        short8 b[8];
        #pragma unroll
        for (int ks = 0; ks < 8; ++ks)
            b[ks] = *reinterpret_cast<const short8*>(bp + ks * 16);

        floatx16 acc;
        #pragma unroll
        for (int i = 0; i < 16; ++i) acc[i] = 0.f;
        #pragma unroll
        for (int ks = 0; ks < 8; ++ks)
            acc = __builtin_amdgcn_mfma_f32_32x32x16_bf16(a[ks], b[ks], acc, 0, 0, 0);

        #pragma unroll
        for (int r = 0; r < 16; ++r) {
            const float ssel = (labj == labi[r]) ? sqjb : sqj;
            const float t = fmaf(-2.f, acc[r], ssel);
            mx[r] = fmaxf(mx[r], t);
            mn[r] = fminf(mn[r], t);
        }
    }

    // reduce across the 32 lanes sharing each (r, hi) row
    #pragma unroll
    for (int r = 0; r < 16; ++r) {
        #pragma unroll
        for (int mk = 1; mk < 32; mk <<= 1) {
            mx[r] = fmaxf(mx[r], __shfl_xor(mx[r], mk, 64));
            mn[r] = fminf(mn[r], __shfl_xor(mn[r], mk, 64));
        }
    }
    if (l31 == 0) {
        #pragma unroll
        for (int r = 0; r < 16; ++r) {
            const int i = rowbase + (r & 3) + 8 * (r >> 2) + 4 * hi;
            const float sqi = sq[i];
            d2p[split * B_ROWS + i] = sqi + (mx[r] - BIAS);  // hardest-pos d^2
            d2n[split * B_ROWS + i] = sqi + mn[r];           // hardest-neg d^2
        }
    }
}

// ---------------- combine: splits -> per-row loss -> scalar ----------------
__global__ __launch_bounds__(256) void combine_kernel(
    const float* __restrict__ d2p, const float* __restrict__ d2n,
    float* __restrict__ acc_sum, int* __restrict__ done,
    float* __restrict__ out) {
    const int row = blockIdx.x * 256 + threadIdx.x;
    float p = -INFINITY, n = INFINITY;
    #pragma unroll
    for (int s = 0; s < NSPLIT; ++s) {
        p = fmaxf(p, d2p[s * B_ROWS + row]);
        n = fminf(n, d2n[s * B_ROWS + row]);
    }
    float v = fmaxf(sqrtf(fmaxf(p, 0.f)) - sqrtf(fmaxf(n, 0.f)) + 1.0f, 0.f);
    #pragma unroll
    for (int mk = 1; mk < 64; mk <<= 1) v += __shfl_xor(v, mk, 64);
    __shared__ float sv[4];
    const int wv = threadIdx.x >> 6;
    if ((threadIdx.x & 63) == 0) sv[wv] = v;
    __syncthreads();
    if (threadIdx.x == 0) {
        atomicAdd(acc_sum, sv[0] + sv[1] + sv[2] + sv[3]);
        __threadfence();
        const int old = atomicAdd(done, 1);
        if (old == (int)gridDim.x - 1) {
            const float fs = atomicAdd(acc_sum, 0.f);   // coherent read
            out[0] = fs / (float)B_ROWS;
        }
    }
}

// ---------------- launch ----------------
extern "C" void kernel_launch(void* const* d_in, const int* in_sizes, int n_in,
                              void* d_out, int out_size, void* d_ws, size_t ws_size,
                              hipStream_t stream) {
    const float* x   = (const float*)d_in[0];
    const int*   lab = (const int*)d_in[1];
    float*       out = (float*)d_out;

    char* ws = (char*)d_ws;
    __hip_bfloat16* xb = (__hip_bfloat16*)ws;
    float* sq      = (float*)(ws + OFF_SQ);
    float* d2p     = (float*)(ws + OFF_D2P);
    float* d2n     = (float*)(ws + OFF_D2N);
    float* acc_sum = (float*)(ws + OFF_ACC);
    int*   done    = (int*)(ws + OFF_ACC + 4);

    prep_kernel<<<B_ROWS / 4, 256, 0, stream>>>(x, xb, sq, acc_sum, done);
    main_kernel<<<dim3(NRB, NSPLIT), 256, 0, stream>>>(xb, sq, lab, d2p, d2n);
    combine_kernel<<<B_ROWS / 256, 256, 0, stream>>>(d2p, d2n, acc_sum, done, out);
}

// Round 4
// 79.037 us; speedup vs baseline: 1.0608x; 1.0608x over previous
//
#include <hip/hip_runtime.h>
#include <hip/hip_bf16.h>

typedef __attribute__((ext_vector_type(8))) short short8;
typedef __attribute__((ext_vector_type(4))) float floatx4;

#define B_ROWS 8192
#define DIM    128
#define NSPLIT 16
#define JSPAN  (B_ROWS / NSPLIT)        // 512 cols per split
#define NTILE  (JSPAN / 16)             // 32 j-tiles of 16 cols
#define WAVES  4
#define RPW    32                       // rows per wave (2 x 16-row MFMA sets)
#define BM     (WAVES * RPW)            // 128 rows per block
#define NRB    (B_ROWS / BM)            // 64 row-blocks
#define BIAS   4096.0f

// ws layout
#define OFF_SQ   (2u << 20)
#define OFF_D2P  (OFF_SQ + (64u << 10))
#define OFF_D2N  (OFF_D2P + (512u << 10))
#define OFF_ACC  (OFF_D2N + (512u << 10))   // float sum, int done

// ---------------- prep: f32 -> bf16 + squared norms + init accumulators ----------------
__global__ __launch_bounds__(256) void prep_kernel(const float* __restrict__ x,
                                                   __hip_bfloat16* __restrict__ xb,
                                                   float* __restrict__ sq,
                                                   float* __restrict__ acc_sum,
                                                   int* __restrict__ done) {
    if (blockIdx.x == 0 && threadIdx.x == 0) { acc_sum[0] = 0.f; done[0] = 0; }
    const int row  = blockIdx.x * 4 + (threadIdx.x >> 6);
    const int lane = threadIdx.x & 63;
    const float2 v = *reinterpret_cast<const float2*>(x + row * DIM + lane * 2);
    __hip_bfloat162 b2;
    b2.x = __float2bfloat16(v.x);
    b2.y = __float2bfloat16(v.y);
    *reinterpret_cast<__hip_bfloat162*>(xb + row * DIM + lane * 2) = b2;
    float s = v.x * v.x + v.y * v.y;
    #pragma unroll
    for (int m = 1; m < 64; m <<= 1) s += __shfl_xor(s, m, 64);
    if (lane == 0) sq[row] = s;
}

// ---------------- main: barrier-free Gram + biased hardest pos/neg ----------------
// grid = (NRB, NSPLIT), block = 256 (4 independent waves), 16x16x32 MFMA.
// Wave owns 32 rows (two 16-row sets); streams 512 cols in 16-col tiles with
// register double-buffer prefetch.  t = sq_j - 2*dot + BIAS*same.
// max over all t = hardest_pos + BIAS; min over all t = hardest_neg.
__global__ __launch_bounds__(256, 4) void main_kernel(
    const __hip_bfloat16* __restrict__ xb,
    const float* __restrict__ sq,
    const int*  __restrict__ lab,
    float* __restrict__ d2p,   // [NSPLIT][B_ROWS]
    float* __restrict__ d2n) { // [NSPLIT][B_ROWS]
    const int tid  = threadIdx.x;
    const int lane = tid & 63;
    const int wave = tid >> 6;
    const int l15  = lane & 15;
    const int g    = lane >> 4;          // 0..3
    const int rowbase = blockIdx.x * BM + wave * RPW;
    const int split   = blockIdx.y;
    const int jstart  = split * JSPAN;

    // A fragments: 2 sets x 16 rows x 128 k.
    // mfma_f32_16x16x32_bf16 A layout: row = lane&15, k = kk*32 + (lane>>4)*8 + e
    short8 a0[4], a1[4];
    {
        const __hip_bfloat16* ap0 = xb + (size_t)(rowbase + l15) * DIM + g * 8;
        const __hip_bfloat16* ap1 = ap0 + 16 * DIM;
        #pragma unroll
        for (int kk = 0; kk < 4; ++kk) {
            a0[kk] = *reinterpret_cast<const short8*>(ap0 + kk * 32);
            a1[kk] = *reinterpret_cast<const short8*>(ap1 + kk * 32);
        }
    }
    // Labels of owned rows per C/D reg (row = (lane>>4)*4 + q)
    int labi0[4], labi1[4];
    #pragma unroll
    for (int q = 0; q < 4; ++q) {
        labi0[q] = lab[rowbase + g * 4 + q];
        labi1[q] = lab[rowbase + 16 + g * 4 + q];
    }

    float mx0[4], mn0[4], mx1[4], mn1[4];
    #pragma unroll
    for (int q = 0; q < 4; ++q) {
        mx0[q] = -INFINITY; mx1[q] = -INFINITY;
        mn0[q] =  INFINITY; mn1[q] =  INFINITY;
    }

    // B column base: col = jbase + (lane&15), k = kk*32 + (lane>>4)*8 + e
    const __hip_bfloat16* bbase = xb + (size_t)(jstart + l15) * DIM + g * 8;

    short8 bA[4], bB[4];
    float sqA, sqB; int labA, labB;
    #pragma unroll
    for (int kk = 0; kk < 4; ++kk)
        bA[kk] = *reinterpret_cast<const short8*>(bbase + kk * 32);
    sqA  = sq[jstart + l15];
    labA = lab[jstart + l15];

    #define COMPUTE(bb, sqj, labj)                                              \
    do {                                                                        \
        floatx4 acc0 = {0.f, 0.f, 0.f, 0.f}, acc1 = {0.f, 0.f, 0.f, 0.f};       \
        _Pragma("unroll")                                                       \
        for (int kk = 0; kk < 4; ++kk) {                                        \
            acc0 = __builtin_amdgcn_mfma_f32_16x16x32_bf16(a0[kk], bb[kk], acc0, 0, 0, 0); \
            acc1 = __builtin_amdgcn_mfma_f32_16x16x32_bf16(a1[kk], bb[kk], acc1, 0, 0, 0); \
        }                                                                       \
        const float sqjb = (sqj) + BIAS;                                        \
        _Pragma("unroll")                                                       \
        for (int q = 0; q < 4; ++q) {                                           \
            const float t0 = fmaf(-2.f, acc0[q], ((labj) == labi0[q]) ? sqjb : (sqj)); \
            mx0[q] = fmaxf(mx0[q], t0);                                         \
            mn0[q] = fminf(mn0[q], t0);                                         \
            const float t1 = fmaf(-2.f, acc1[q], ((labj) == labi1[q]) ? sqjb : (sqj)); \
            mx1[q] = fmaxf(mx1[q], t1);                                         \
            mn1[q] = fminf(mn1[q], t1);                                         \
        }                                                                       \
    } while (0)

    for (int jt = 0; jt < NTILE; jt += 2) {
        // prefetch tile jt+1 into B
        {
            const __hip_bfloat16* bp = bbase + (size_t)(jt + 1) * 16 * DIM;
            #pragma unroll
            for (int kk = 0; kk < 4; ++kk)
                bB[kk] = *reinterpret_cast<const short8*>(bp + kk * 32);
            sqB  = sq[jstart + (jt + 1) * 16 + l15];
            labB = lab[jstart + (jt + 1) * 16 + l15];
        }
        COMPUTE(bA, sqA, labA);
        // prefetch tile jt+2 into A
        if (jt + 2 < NTILE) {
            const __hip_bfloat16* bp = bbase + (size_t)(jt + 2) * 16 * DIM;
            #pragma unroll
            for (int kk = 0; kk < 4; ++kk)
                bA[kk] = *reinterpret_cast<const short8*>(bp + kk * 32);
            sqA  = sq[jstart + (jt + 2) * 16 + l15];
            labA = lab[jstart + (jt + 2) * 16 + l15];
        }
        COMPUTE(bB, sqB, labB);
    }
    #undef COMPUTE

    // reduce over the 16 cols held by the 16 lanes of each g-group
    #pragma unroll
    for (int q = 0; q < 4; ++q) {
        #pragma unroll
        for (int mk = 1; mk < 16; mk <<= 1) {
            mx0[q] = fmaxf(mx0[q], __shfl_xor(mx0[q], mk, 64));
            mn0[q] = fminf(mn0[q], __shfl_xor(mn0[q], mk, 64));
            mx1[q] = fmaxf(mx1[q], __shfl_xor(mx1[q], mk, 64));
            mn1[q] = fminf(mn1[q], __shfl_xor(mn1[q], mk, 64));
        }
    }
    if (l15 == 0) {
        #pragma unroll
        for (int q = 0; q < 4; ++q) {
            const int i0 = rowbase + g * 4 + q;
            const int i1 = rowbase + 16 + g * 4 + q;
            d2p[split * B_ROWS + i0] = sq[i0] + (mx0[q] - BIAS);
            d2n[split * B_ROWS + i0] = sq[i0] + mn0[q];
            d2p[split * B_ROWS + i1] = sq[i1] + (mx1[q] - BIAS);
            d2n[split * B_ROWS + i1] = sq[i1] + mn1[q];
        }
    }
}

// ---------------- combine: splits -> per-row loss -> scalar ----------------
__global__ __launch_bounds__(256) void combine_kernel(
    const float* __restrict__ d2p, const float* __restrict__ d2n,
    float* __restrict__ acc_sum, int* __restrict__ done,
    float* __restrict__ out) {
    const int row = blockIdx.x * 256 + threadIdx.x;
    float p = -INFINITY, n = INFINITY;
    #pragma unroll
    for (int s = 0; s < NSPLIT; ++s) {
        p = fmaxf(p, d2p[s * B_ROWS + row]);
        n = fminf(n, d2n[s * B_ROWS + row]);
    }
    float v = fmaxf(sqrtf(fmaxf(p, 0.f)) - sqrtf(fmaxf(n, 0.f)) + 1.0f, 0.f);
    #pragma unroll
    for (int mk = 1; mk < 64; mk <<= 1) v += __shfl_xor(v, mk, 64);
    __shared__ float sv[4];
    const int wv = threadIdx.x >> 6;
    if ((threadIdx.x & 63) == 0) sv[wv] = v;
    __syncthreads();
    if (threadIdx.x == 0) {
        atomicAdd(acc_sum, sv[0] + sv[1] + sv[2] + sv[3]);
        __threadfence();
        const int old = atomicAdd(done, 1);
        if (old == (int)gridDim.x - 1) {
            const float fs = atomicAdd(acc_sum, 0.f);   // coherent read
            out[0] = fs / (float)B_ROWS;
        }
    }
}

// ---------------- launch ----------------
extern "C" void kernel_launch(void* const* d_in, const int* in_sizes, int n_in,
                              void* d_out, int out_size, void* d_ws, size_t ws_size,
                              hipStream_t stream) {
    const float* x   = (const float*)d_in[0];
    const int*   lab = (const int*)d_in[1];
    float*       out = (float*)d_out;

    char* ws = (char*)d_ws;
    __hip_bfloat16* xb = (__hip_bfloat16*)ws;
    float* sq      = (float*)(ws + OFF_SQ);
    float* d2p     = (float*)(ws + OFF_D2P);
    float* d2n     = (float*)(ws + OFF_D2N);
    float* acc_sum = (float*)(ws + OFF_ACC);
    int*   done    = (int*)(ws + OFF_ACC + 4);

    prep_kernel<<<B_ROWS / 4, 256, 0, stream>>>(x, xb, sq, acc_sum, done);
    main_kernel<<<dim3(NRB, NSPLIT), 256, 0, stream>>>(xb, sq, lab, d2p, d2n);
    combine_kernel<<<B_ROWS / 256, 256, 0, stream>>>(d2p, d2n, acc_sum, done, out);
}

// Round 5
// 38.267 us; speedup vs baseline: 2.1910x; 2.0654x over previous
//
#include <hip/hip_runtime.h>
#include <hip/hip_bf16.h>

typedef __attribute__((ext_vector_type(8))) short short8;
typedef __attribute__((ext_vector_type(4))) float floatx4;

#define B_ROWS 8192
#define DIM    128
#define NSPLIT 16
#define JSPAN  (B_ROWS / NSPLIT)        // 512 cols per split
#define NTILE  (JSPAN / 16)             // 32 j-tiles of 16 cols
#define WAVES  4
#define RPW    32                       // rows per wave (2 x 16-row MFMA sets)
#define BM     (WAVES * RPW)            // 128 rows per block
#define NRB    (B_ROWS / BM)            // 64 row-blocks
#define BIAS   4096.0f

// Fragment-ordered buffer xf: for 16-row tile t, k-slice kk (0..3), lane l (0..63):
//   bf16 index = t*2048 + kk*512 + l*8 + e   (e = 0..7)
// encodes element (row = t*16 + (l&15), k = kk*32 + (l>>4)*8 + e) — exactly the
// mfma_f32_16x16x32_bf16 A/B fragment layout, so every frag load is contiguous.

// ws layout
#define OFF_SQ   (2u << 20)
#define OFF_D2P  (OFF_SQ + (64u << 10))
#define OFF_D2N  (OFF_D2P + (512u << 10))
#define OFF_ACC  (OFF_D2N + (512u << 10))   // float sum, int done

// ---------------- prep: f32 -> bf16 fragment-order + squared norms ----------------
__global__ __launch_bounds__(256) void prep_kernel(const float* __restrict__ x,
                                                   __hip_bfloat16* __restrict__ xf,
                                                   float* __restrict__ sq,
                                                   float* __restrict__ acc_sum,
                                                   int* __restrict__ done) {
    if (blockIdx.x == 0 && threadIdx.x == 0) { acc_sum[0] = 0.f; done[0] = 0; }
    const int row  = blockIdx.x * 4 + (threadIdx.x >> 6);
    const int lane = threadIdx.x & 63;   // holds k = 2*lane, 2*lane+1
    const float2 v = *reinterpret_cast<const float2*>(x + row * DIM + lane * 2);
    __hip_bfloat162 b2;
    b2.x = __float2bfloat16(v.x);
    b2.y = __float2bfloat16(v.y);
    // fragment-order address for k0 = 2*lane
    const int kk = lane >> 4;            // k0>>5
    const int g  = (lane >> 2) & 3;      // (k0>>3)&3
    const int e  = (lane & 3) * 2;       // k0&7
    const int idx = (row >> 4) * 2048 + kk * 512 + (g * 16 + (row & 15)) * 8 + e;
    *reinterpret_cast<__hip_bfloat162*>(xf + idx) = b2;
    float s = v.x * v.x + v.y * v.y;
    #pragma unroll
    for (int m = 1; m < 64; m <<= 1) s += __shfl_xor(s, m, 64);
    if (lane == 0) sq[row] = s;
}

// ---------------- main: barrier-free Gram + biased hardest pos/neg ----------------
// Identical structure to round 4; only the A/B fragment loads now come from the
// fragment-ordered xf (contiguous 1KB per load instruction).
__global__ __launch_bounds__(256, 4) void main_kernel(
    const __hip_bfloat16* __restrict__ xf,
    const float* __restrict__ sq,
    const int*  __restrict__ lab,
    float* __restrict__ d2p,   // [NSPLIT][B_ROWS]
    float* __restrict__ d2n) { // [NSPLIT][B_ROWS]
    const int tid  = threadIdx.x;
    const int lane = tid & 63;
    const int wave = tid >> 6;
    const int l15  = lane & 15;
    const int g    = lane >> 4;          // 0..3
    const int rowbase = blockIdx.x * BM + wave * RPW;
    const int split   = blockIdx.y;
    const int jstart  = split * JSPAN;

    // A fragments: 2 sets x 16 rows, contiguous loads from xf
    short8 a0[4], a1[4];
    {
        const __hip_bfloat16* ap = xf + (size_t)(rowbase >> 4) * 2048 + lane * 8;
        #pragma unroll
        for (int kk = 0; kk < 4; ++kk) {
            a0[kk] = *reinterpret_cast<const short8*>(ap + kk * 512);
            a1[kk] = *reinterpret_cast<const short8*>(ap + 2048 + kk * 512);
        }
    }
    // Labels of owned rows per C/D reg (row = (lane>>4)*4 + q)
    int labi0[4], labi1[4];
    #pragma unroll
    for (int q = 0; q < 4; ++q) {
        labi0[q] = lab[rowbase + g * 4 + q];
        labi1[q] = lab[rowbase + 16 + g * 4 + q];
    }

    float mx0[4], mn0[4], mx1[4], mn1[4];
    #pragma unroll
    for (int q = 0; q < 4; ++q) {
        mx0[q] = -INFINITY; mx1[q] = -INFINITY;
        mn0[q] =  INFINITY; mn1[q] =  INFINITY;
    }

    // B tile base in fragment order: tile tj = jstart/16 + jt
    const __hip_bfloat16* bbase = xf + (size_t)(jstart >> 4) * 2048 + lane * 8;

    short8 bA[4], bB[4];
    float sqA, sqB; int labA, labB;
    #pragma unroll
    for (int kk = 0; kk < 4; ++kk)
        bA[kk] = *reinterpret_cast<const short8*>(bbase + kk * 512);
    sqA  = sq[jstart + l15];
    labA = lab[jstart + l15];

    #define COMPUTE(bb, sqj, labj)                                              \
    do {                                                                        \
        floatx4 acc0 = {0.f, 0.f, 0.f, 0.f}, acc1 = {0.f, 0.f, 0.f, 0.f};       \
        _Pragma("unroll")                                                       \
        for (int kk = 0; kk < 4; ++kk) {                                        \
            acc0 = __builtin_amdgcn_mfma_f32_16x16x32_bf16(a0[kk], bb[kk], acc0, 0, 0, 0); \
            acc1 = __builtin_amdgcn_mfma_f32_16x16x32_bf16(a1[kk], bb[kk], acc1, 0, 0, 0); \
        }                                                                       \
        const float sqjb = (sqj) + BIAS;                                        \
        _Pragma("unroll")                                                       \
        for (int q = 0; q < 4; ++q) {                                           \
            const float t0 = fmaf(-2.f, acc0[q], ((labj) == labi0[q]) ? sqjb : (sqj)); \
            mx0[q] = fmaxf(mx0[q], t0);                                         \
            mn0[q] = fminf(mn0[q], t0);                                         \
            const float t1 = fmaf(-2.f, acc1[q], ((labj) == labi1[q]) ? sqjb : (sqj)); \
            mx1[q] = fmaxf(mx1[q], t1);                                         \
            mn1[q] = fminf(mn1[q], t1);                                         \
        }                                                                       \
    } while (0)

    for (int jt = 0; jt < NTILE; jt += 2) {
        // prefetch tile jt+1 into B
        {
            const __hip_bfloat16* bp = bbase + (size_t)(jt + 1) * 2048;
            #pragma unroll
            for (int kk = 0; kk < 4; ++kk)
                bB[kk] = *reinterpret_cast<const short8*>(bp + kk * 512);
            sqB  = sq[jstart + (jt + 1) * 16 + l15];
            labB = lab[jstart + (jt + 1) * 16 + l15];
        }
        COMPUTE(bA, sqA, labA);
        // prefetch tile jt+2 into A
        if (jt + 2 < NTILE) {
            const __hip_bfloat16* bp = bbase + (size_t)(jt + 2) * 2048;
            #pragma unroll
            for (int kk = 0; kk < 4; ++kk)
                bA[kk] = *reinterpret_cast<const short8*>(bp + kk * 512);
            sqA  = sq[jstart + (jt + 2) * 16 + l15];
            labA = lab[jstart + (jt + 2) * 16 + l15];
        }
        COMPUTE(bB, sqB, labB);
    }
    #undef COMPUTE

    // reduce over the 16 cols held by the 16 lanes of each g-group
    #pragma unroll
    for (int q = 0; q < 4; ++q) {
        #pragma unroll
        for (int mk = 1; mk < 16; mk <<= 1) {
            mx0[q] = fmaxf(mx0[q], __shfl_xor(mx0[q], mk, 64));
            mn0[q] = fminf(mn0[q], __shfl_xor(mn0[q], mk, 64));
            mx1[q] = fmaxf(mx1[q], __shfl_xor(mx1[q], mk, 64));
            mn1[q] = fminf(mn1[q], __shfl_xor(mn1[q], mk, 64));
        }
    }
    if (l15 == 0) {
        #pragma unroll
        for (int q = 0; q < 4; ++q) {
            const int i0 = rowbase + g * 4 + q;
            const int i1 = rowbase + 16 + g * 4 + q;
            d2p[split * B_ROWS + i0] = sq[i0] + (mx0[q] - BIAS);
            d2n[split * B_ROWS + i0] = sq[i0] + mn0[q];
            d2p[split * B_ROWS + i1] = sq[i1] + (mx1[q] - BIAS);
            d2n[split * B_ROWS + i1] = sq[i1] + mn1[q];
        }
    }
}

// ---------------- combine: splits -> per-row loss -> scalar ----------------
__global__ __launch_bounds__(256) void combine_kernel(
    const float* __restrict__ d2p, const float* __restrict__ d2n,
    float* __restrict__ acc_sum, int* __restrict__ done,
    float* __restrict__ out) {
    const int row = blockIdx.x * 256 + threadIdx.x;
    float p = -INFINITY, n = INFINITY;
    #pragma unroll
    for (int s = 0; s < NSPLIT; ++s) {
        p = fmaxf(p, d2p[s * B_ROWS + row]);
        n = fminf(n, d2n[s * B_ROWS + row]);
    }
    float v = fmaxf(sqrtf(fmaxf(p, 0.f)) - sqrtf(fmaxf(n, 0.f)) + 1.0f, 0.f);
    #pragma unroll
    for (int mk = 1; mk < 64; mk <<= 1) v += __shfl_xor(v, mk, 64);
    __shared__ float sv[4];
    const int wv = threadIdx.x >> 6;
    if ((threadIdx.x & 63) == 0) sv[wv] = v;
    __syncthreads();
    if (threadIdx.x == 0) {
        atomicAdd(acc_sum, sv[0] + sv[1] + sv[2] + sv[3]);
        __threadfence();
        const int old = atomicAdd(done, 1);
        if (old == (int)gridDim.x - 1) {
            const float fs = atomicAdd(acc_sum, 0.f);   // coherent read
            out[0] = fs / (float)B_ROWS;
        }
    }
}

// ---------------- launch ----------------
extern "C" void kernel_launch(void* const* d_in, const int* in_sizes, int n_in,
                              void* d_out, int out_size, void* d_ws, size_t ws_size,
                              hipStream_t stream) {
    const float* x   = (const float*)d_in[0];
    const int*   lab = (const int*)d_in[1];
    float*       out = (float*)d_out;

    char* ws = (char*)d_ws;
    __hip_bfloat16* xf = (__hip_bfloat16*)ws;
    float* sq      = (float*)(ws + OFF_SQ);
    float* d2p     = (float*)(ws + OFF_D2P);
    float* d2n     = (float*)(ws + OFF_D2N);
    float* acc_sum = (float*)(ws + OFF_ACC);
    int*   done    = (int*)(ws + OFF_ACC + 4);

    prep_kernel<<<B_ROWS / 4, 256, 0, stream>>>(x, xf, sq, acc_sum, done);
    main_kernel<<<dim3(NRB, NSPLIT), 256, 0, stream>>>(xf, sq, lab, d2p, d2n);
    combine_kernel<<<B_ROWS / 256, 256, 0, stream>>>(d2p, d2n, acc_sum, done, out);
}

// Round 6
// 34.657 us; speedup vs baseline: 2.4193x; 1.1042x over previous
//
#include <hip/hip_runtime.h>
#include <hip/hip_bf16.h>

typedef __attribute__((ext_vector_type(8))) short short8;
typedef __attribute__((ext_vector_type(4))) float floatx4;

#define B_ROWS 8192
#define DIM    128
#define NSPLIT 16
#define JSPAN  (B_ROWS / NSPLIT)        // 512 cols per split
#define NTILE  (JSPAN / 16)             // 32 j-tiles of 16 cols
#define WAVES  4
#define RPW    64                       // rows per wave (4 x 16-row MFMA sets)
#define BM     (WAVES * RPW)            // 256 rows per block
#define NRB    (B_ROWS / BM)            // 32 row-blocks -> 512 blocks = 2/CU
#define BIAS   4096.0f

// Fragment-ordered buffer xf: for 16-row tile t, k-slice kk (0..3), lane l (0..63):
//   bf16 index = t*2048 + kk*512 + l*8 + e   (e = 0..7)
// encodes element (row = t*16 + (l&15), k = kk*32 + (l>>4)*8 + e) — exactly the
// mfma_f32_16x16x32_bf16 A/B fragment layout, so every frag load is contiguous.

// ws layout
#define OFF_SQ   (2u << 20)
#define OFF_D2P  (OFF_SQ + (64u << 10))
#define OFF_D2N  (OFF_D2P + (512u << 10))
#define OFF_ACC  (OFF_D2N + (512u << 10))   // float sum, int done

// ---------------- prep: f32 -> bf16 fragment-order + squared norms ----------------
__global__ __launch_bounds__(256) void prep_kernel(const float* __restrict__ x,
                                                   __hip_bfloat16* __restrict__ xf,
                                                   float* __restrict__ sq,
                                                   float* __restrict__ acc_sum,
                                                   int* __restrict__ done) {
    if (blockIdx.x == 0 && threadIdx.x == 0) { acc_sum[0] = 0.f; done[0] = 0; }
    const int row  = blockIdx.x * 4 + (threadIdx.x >> 6);
    const int lane = threadIdx.x & 63;   // holds k = 2*lane, 2*lane+1
    const float2 v = *reinterpret_cast<const float2*>(x + row * DIM + lane * 2);
    __hip_bfloat162 b2;
    b2.x = __float2bfloat16(v.x);
    b2.y = __float2bfloat16(v.y);
    // fragment-order address for k0 = 2*lane
    const int kk = lane >> 4;            // k0>>5
    const int g  = (lane >> 2) & 3;      // (k0>>3)&3
    const int e  = (lane & 3) * 2;       // k0&7
    const int idx = (row >> 4) * 2048 + kk * 512 + (g * 16 + (row & 15)) * 8 + e;
    *reinterpret_cast<__hip_bfloat162*>(xf + idx) = b2;
    float s = v.x * v.x + v.y * v.y;
    #pragma unroll
    for (int m = 1; m < 64; m <<= 1) s += __shfl_xor(s, m, 64);
    if (lane == 0) sq[row] = s;
}

// ---------------- main: barrier-free Gram + biased hardest pos/neg ----------------
// grid = (NRB, NSPLIT), block = 256 (4 independent waves), 2 waves/SIMD.
// Wave owns 64 rows (four 16-row sets) -> each B fragment feeds 4 MFMAs,
// halving per-CU L1 bandwidth demand per unit of compute.
// t = sq_j - 2*dot + BIAS*same.  max t = hardest_pos + BIAS; min t = hardest_neg.
__global__ __launch_bounds__(256, 2) void main_kernel(
    const __hip_bfloat16* __restrict__ xf,
    const float* __restrict__ sq,
    const int*  __restrict__ lab,
    float* __restrict__ d2p,   // [NSPLIT][B_ROWS]
    float* __restrict__ d2n) { // [NSPLIT][B_ROWS]
    const int tid  = threadIdx.x;
    const int lane = tid & 63;
    const int wave = tid >> 6;
    const int l15  = lane & 15;
    const int g    = lane >> 4;          // 0..3
    const int rowbase = blockIdx.x * BM + wave * RPW;
    const int split   = blockIdx.y;
    const int jstart  = split * JSPAN;

    // A fragments: 4 sets x 16 rows, contiguous loads from xf
    short8 a[4][4];
    #pragma unroll
    for (int s = 0; s < 4; ++s) {
        const __hip_bfloat16* ap = xf + ((size_t)(rowbase >> 4) + s) * 2048 + lane * 8;
        #pragma unroll
        for (int kk = 0; kk < 4; ++kk)
            a[s][kk] = *reinterpret_cast<const short8*>(ap + kk * 512);
    }
    // Labels of owned rows per C/D reg (row = s*16 + g*4 + q)
    int labi[4][4];
    #pragma unroll
    for (int s = 0; s < 4; ++s)
        #pragma unroll
        for (int q = 0; q < 4; ++q)
            labi[s][q] = lab[rowbase + s * 16 + g * 4 + q];

    float mx[4][4], mn[4][4];
    #pragma unroll
    for (int s = 0; s < 4; ++s)
        #pragma unroll
        for (int q = 0; q < 4; ++q) { mx[s][q] = -INFINITY; mn[s][q] = INFINITY; }

    const __hip_bfloat16* bbase = xf + (size_t)(jstart >> 4) * 2048 + lane * 8;

    short8 bA[4], bB[4];
    float sqA, sqB; int labA, labB;
    #pragma unroll
    for (int kk = 0; kk < 4; ++kk) {
        bA[kk] = *reinterpret_cast<const short8*>(bbase + kk * 512);
        bB[kk] = *reinterpret_cast<const short8*>(bbase + 2048 + kk * 512);
    }
    sqA  = sq[jstart + l15];          labA = lab[jstart + l15];
    sqB  = sq[jstart + 16 + l15];     labB = lab[jstart + 16 + l15];

    float tA[4][4], tB[4][4];

    #define MFMA_TILE(BB, T, SQJ, LABJ)                                         \
    do {                                                                        \
        floatx4 acc[4];                                                         \
        _Pragma("unroll")                                                       \
        for (int s = 0; s < 4; ++s) acc[s] = (floatx4){0.f, 0.f, 0.f, 0.f};     \
        _Pragma("unroll")                                                       \
        for (int kk = 0; kk < 4; ++kk) {                                        \
            _Pragma("unroll")                                                   \
            for (int s = 0; s < 4; ++s)                                         \
                acc[s] = __builtin_amdgcn_mfma_f32_16x16x32_bf16(a[s][kk], BB[kk], acc[s], 0, 0, 0); \
        }                                                                       \
        const float sqjb = (SQJ) + BIAS;                                        \
        _Pragma("unroll")                                                       \
        for (int s = 0; s < 4; ++s) {                                           \
            _Pragma("unroll")                                                   \
            for (int q = 0; q < 4; ++q)                                         \
                T[s][q] = fmaf(-2.f, acc[s][q], ((LABJ) == labi[s][q]) ? sqjb : (SQJ)); \
        }                                                                       \
    } while (0)

    for (int jt = 0; jt < NTILE; jt += 2) {
        MFMA_TILE(bA, tA, sqA, labA);
        if (jt + 2 < NTILE) {   // prefetch tile jt+2 into the A slot
            const __hip_bfloat16* bp = bbase + (size_t)(jt + 2) * 2048;
            #pragma unroll
            for (int kk = 0; kk < 4; ++kk)
                bA[kk] = *reinterpret_cast<const short8*>(bp + kk * 512);
            sqA  = sq[jstart + (jt + 2) * 16 + l15];
            labA = lab[jstart + (jt + 2) * 16 + l15];
        }
        MFMA_TILE(bB, tB, sqB, labB);
        if (jt + 3 < NTILE) {   // prefetch tile jt+3 into the B slot
            const __hip_bfloat16* bp = bbase + (size_t)(jt + 3) * 2048;
            #pragma unroll
            for (int kk = 0; kk < 4; ++kk)
                bB[kk] = *reinterpret_cast<const short8*>(bp + kk * 512);
            sqB  = sq[jstart + (jt + 3) * 16 + l15];
            labB = lab[jstart + (jt + 3) * 16 + l15];
        }
        // joint merge: v_max3 / v_min3 per cell pair
        #pragma unroll
        for (int s = 0; s < 4; ++s)
            #pragma unroll
            for (int q = 0; q < 4; ++q) {
                mx[s][q] = fmaxf(fmaxf(mx[s][q], tA[s][q]), tB[s][q]);
                mn[s][q] = fminf(fminf(mn[s][q], tA[s][q]), tB[s][q]);
            }
    }
    #undef MFMA_TILE

    // reduce over the 16 cols held by the 16 lanes of each g-group
    #pragma unroll
    for (int s = 0; s < 4; ++s)
        #pragma unroll
        for (int q = 0; q < 4; ++q) {
            #pragma unroll
            for (int mk = 1; mk < 16; mk <<= 1) {
                mx[s][q] = fmaxf(mx[s][q], __shfl_xor(mx[s][q], mk, 64));
                mn[s][q] = fminf(mn[s][q], __shfl_xor(mn[s][q], mk, 64));
            }
        }
    if (l15 == 0) {
        #pragma unroll
        for (int s = 0; s < 4; ++s)
            #pragma unroll
            for (int q = 0; q < 4; ++q) {
                const int i = rowbase + s * 16 + g * 4 + q;
                const float sqi = sq[i];
                d2p[split * B_ROWS + i] = sqi + (mx[s][q] - BIAS);
                d2n[split * B_ROWS + i] = sqi + mn[s][q];
            }
    }
}

// ---------------- combine: splits -> per-row loss -> scalar ----------------
__global__ __launch_bounds__(256) void combine_kernel(
    const float* __restrict__ d2p, const float* __restrict__ d2n,
    float* __restrict__ acc_sum, int* __restrict__ done,
    float* __restrict__ out) {
    const int row = blockIdx.x * 256 + threadIdx.x;
    float p = -INFINITY, n = INFINITY;
    #pragma unroll
    for (int s = 0; s < NSPLIT; ++s) {
        p = fmaxf(p, d2p[s * B_ROWS + row]);
        n = fminf(n, d2n[s * B_ROWS + row]);
    }
    float v = fmaxf(sqrtf(fmaxf(p, 0.f)) - sqrtf(fmaxf(n, 0.f)) + 1.0f, 0.f);
    #pragma unroll
    for (int mk = 1; mk < 64; mk <<= 1) v += __shfl_xor(v, mk, 64);
    __shared__ float sv[4];
    const int wv = threadIdx.x >> 6;
    if ((threadIdx.x & 63) == 0) sv[wv] = v;
    __syncthreads();
    if (threadIdx.x == 0) {
        atomicAdd(acc_sum, sv[0] + sv[1] + sv[2] + sv[3]);
        __threadfence();
        const int old = atomicAdd(done, 1);
        if (old == (int)gridDim.x - 1) {
            const float fs = atomicAdd(acc_sum, 0.f);   // coherent read
            out[0] = fs / (float)B_ROWS;
        }
    }
}

// ---------------- launch ----------------
extern "C" void kernel_launch(void* const* d_in, const int* in_sizes, int n_in,
                              void* d_out, int out_size, void* d_ws, size_t ws_size,
                              hipStream_t stream) {
    const float* x   = (const float*)d_in[0];
    const int*   lab = (const int*)d_in[1];
    float*       out = (float*)d_out;

    char* ws = (char*)d_ws;
    __hip_bfloat16* xf = (__hip_bfloat16*)ws;
    float* sq      = (float*)(ws + OFF_SQ);
    float* d2p     = (float*)(ws + OFF_D2P);
    float* d2n     = (float*)(ws + OFF_D2N);
    float* acc_sum = (float*)(ws + OFF_ACC);
    int*   done    = (int*)(ws + OFF_ACC + 4);

    prep_kernel<<<B_ROWS / 4, 256, 0, stream>>>(x, xf, sq, acc_sum, done);
    main_kernel<<<dim3(NRB, NSPLIT), 256, 0, stream>>>(xf, sq, lab, d2p, d2n);
    combine_kernel<<<B_ROWS / 256, 256, 0, stream>>>(d2p, d2n, acc_sum, done, out);
}